// Round 9
// baseline (243.555 us; speedup 1.0000x reference)
//
#include <hip/hip_runtime.h>
#include <cstdint>
#include <cstddef>

#define B_N   16
#define A_N   8732
#define C_N   91
#define FG_N  90
#define K_TOP 400
#define D_N   200
#define NTASK (B_N * FG_N)   // 1440
#define K4_T  1024           // k4 threads (16 blocks is latency-bound)
#define NBIN  2048           // k23 histogram bins (8 KB)
#define K23_T 512            // k23 threads: 8 waves (multiple of 4 SIMDs)
#define NW    8              // k23 waves per block
#define K1B_T 512            // k1 threads
#define K1_ANB 64            // anchors per k1 block; 139712/64 = 2183 exact

// ---------------------------------------------------------------------------
// K1: softmax + decode. Coalesced LDS staging + register/shfl softmax
//   (bit-exact, verified absmax=0.0) + coalesced float4 write-out.
//   64 anchors x 512 threads (verified R7/R8).
// ---------------------------------------------------------------------------
__global__ __launch_bounds__(K1B_T) void k1_softmax_decode(
    const float* __restrict__ cls, const float* __restrict__ reg,
    const float* __restrict__ anc, float* __restrict__ probs_t,
    float* __restrict__ boxes)
{
#pragma clang fp contract(off)
  __shared__ __align__(16) float lds[K1_ANB * C_N];   // 5824 floats = 23296 B
  const int tid = threadIdx.x;
  const int gi0 = blockIdx.x * K1_ANB;

  // stage-in: block slab = 64 anchors x 91 classes, contiguous in (b,a,c)
  {
    const float4* src = (const float4*)cls + ((size_t)gi0 * C_N >> 2);
    float4* dst = (float4*)lds;
    constexpr int NF4 = (K1_ANB * C_N) / 4;           // 1456
    for (int t = tid; t < NF4; t += K1B_T) dst[t] = src[t];
  }
  __syncthreads();

  const int g  = tid >> 3;                     // local anchor 0..63
  const int l8 = tid & 7;                      // class segment 0..7
  const int gi = gi0 + g;
  const int b  = gi / A_N;
  const int a  = gi - b * A_N;
  const int c0 = l8 * 12;
  const float* lg = lds + g * C_N;

  float v[12];
#pragma unroll
  for (int i = 0; i < 12; ++i) {
    int c = c0 + i;
    v[i] = (c < C_N) ? lg[c] : -__builtin_huge_valf();
  }
  float m = v[0];
#pragma unroll
  for (int i = 1; i < 12; ++i) m = fmaxf(m, v[i]);
#pragma unroll
  for (int d = 1; d < 8; d <<= 1) m = fmaxf(m, __shfl_xor(m, d, 64));

  float e[12];
  float s = 0.0f;
#pragma unroll
  for (int i = 0; i < 12; ++i) {               // exp(-inf)=0; s+0.0f==s
    e[i] = expf(v[i] - m);
    s += e[i];
  }
#pragma unroll
  for (int d = 1; d < 8; d <<= 1) s += __shfl_xor(s, d, 64);

  // probs back into LDS (thread-private slots; overwrite logits)
#pragma unroll
  for (int i = 0; i < 12; ++i) {
    int c = c0 + i;
    if (c < C_N) lds[g * C_N + c] = e[i] / s;
  }

  // decode on the 7-class lane (registers/global only; no LDS hazard)
  if (l8 == 7) {
    float4 rl = *(const float4*)(reg + (size_t)gi * 4);
    float4 an = *(const float4*)(anc + (size_t)a * 4);
    float wa = an.z - an.x;
    float ha = an.w - an.y;
    float cxa = an.x + 0.5f * wa;
    float cya = an.y + 0.5f * ha;
    float dx = rl.x / 10.0f;
    float dy = rl.y / 10.0f;
    const float clipv = 4.135166556742356f;   // log(1000/16)
    float dw = fminf(rl.z / 5.0f, clipv);
    float dh = fminf(rl.w / 5.0f, clipv);
    float t1 = dx * wa;  float cx = t1 + cxa;
    float t2 = dy * ha;  float cy = t2 + cya;
    float w = expf(dw) * wa;
    float h = expf(dh) * ha;
    float4 out;
    out.x = fminf(fmaxf(cx - 0.5f * w, 0.0f), 300.0f);
    out.y = fminf(fmaxf(cy - 0.5f * h, 0.0f), 300.0f);
    out.z = fminf(fmaxf(cx + 0.5f * w, 0.0f), 300.0f);
    out.w = fminf(fmaxf(cy + 0.5f * h, 0.0f), 300.0f);
    *(float4*)(boxes + (size_t)gi * 4) = out;
  }
  __syncthreads();

  // coalesced write-out: 90 rows x 16 anchor-quads = 1440 float4 units
  constexpr int NU = FG_N * (K1_ANB / 4);      // 1440
  for (int u = tid; u < NU; u += K1B_T) {
    int r  = u >> 4;                           // fg row (class r+1)
    int q  = u & 15;                           // anchor quad
    int la = q << 2;
    int gja = gi0 + la;
    int b0 = gja / A_N;
    int b3 = (gja + 3) / A_N;
    float4 val;
    val.x = lds[(la + 0) * C_N + r + 1];
    val.y = lds[(la + 1) * C_N + r + 1];
    val.z = lds[(la + 2) * C_N + r + 1];
    val.w = lds[(la + 3) * C_N + r + 1];
    if (b0 == b3) {
      int a0 = gja - b0 * A_N;
      *(float4*)(probs_t + ((size_t)b0 * FG_N + r) * A_N + a0) = val;
    } else {                                   // image-boundary quad
      float tmp[4] = {val.x, val.y, val.z, val.w};
#pragma unroll
      for (int k = 0; k < 4; ++k) {
        int gj = gja + k;
        int bk = gj / A_N;
        int ak = gj - bk * A_N;
        probs_t[((size_t)bk * FG_N + r) * A_N + ak] = tmp[k];
      }
    }
  }
}

// ---------------------------------------------------------------------------
// shared helper: descending rank-select over a 256-chunked histogram.
// Thread-count-safe: threads >=256 skip compute but hit every barrier.
// nbins must be a multiple of 256 (per = nbins/256 bins per thread).
// (only used on the rare exact-fallback paths)
// ---------------------------------------------------------------------------
__device__ __forceinline__ void scan_select(int* hist, int nbins, int need,
                                            int tid, int* chunk, int* res)
{
  int per = nbins >> 8;            // 2048 -> 8, 1024 -> 4, 256 -> 1
  if (tid < 256) {
    int s = 0;
    for (int i = 0; i < per; ++i) s += hist[tid * per + i];
    chunk[tid] = s;
  }
  __syncthreads();
  if (tid == 0) {
    int cum = 0;
    for (int t2 = 255; t2 >= 0; --t2) { int v = chunk[t2]; chunk[t2] = cum; cum += v; }
  }
  __syncthreads();
  if (tid < 256) {
    int cum = chunk[tid];          // count in strictly-higher chunks
    for (int i = per - 1; i >= 0; --i) {
      int bn = tid * per + i;
      int h = hist[bn];
      if (cum < need && need <= cum + h) { res[0] = bn; res[1] = cum; }
      cum += h;
    }
  }
  __syncthreads();
}

// ---------------------------------------------------------------------------
// parallel descending exclusive scan over chunk[256], done by wave 0 alone.
// chunk[t] <- sum_{t' > t} chunk_in[t'];  *s_total <- sum_all.
// Caller must barrier before (chunk populated) and after (results visible).
// ---------------------------------------------------------------------------
__device__ __forceinline__ void desc_scan256(int* chunk, int* s_total, int tid)
{
  if (tid < 64) {
    const int l = tid;
    int e0 = chunk[4 * l + 0];
    int e1 = chunk[4 * l + 1];
    int e2 = chunk[4 * l + 2];
    int e3 = chunk[4 * l + 3];
    int ls = e0 + e1 + e2 + e3;
    int suf = ls;
#pragma unroll
    for (int d = 1; d < 64; d <<= 1) {
      int o = __shfl(suf, l + d, 64);
      if (l + d < 64) suf += o;
    }
    int excl = suf - ls;                 // sum over lanes strictly above
    chunk[4 * l + 3] = excl;
    chunk[4 * l + 2] = excl + e3;
    chunk[4 * l + 1] = excl + e3 + e2;
    chunk[4 * l + 0] = excl + e3 + e2 + e1;
    if (l == 0) *s_total = suf;
  }
}

// ---------------------------------------------------------------------------
// K23: FUSED top-400 + NMS, one block (8 waves = 2 per SIMD, 512 threads)
// per (image, fg-class). 256t left 22.5/32 CU wave-slots used (5.625
// blocks x 4 waves); 512t fills all 32 slots (4 blocks/CU resident,
// 1024+416 scheduling rounds -- fine for a throughput-bound kernel).
// __launch_bounds__(512,8) caps VGPR at 64 so 8 waves/SIMD actually fit;
// the R8 register-cache is dropped to stay under the cap (it was worth
// -2us; FETCH_SIZE reverts to ~58MB by design).
//   Phase 1: histogram rank-scatter over monotone 11-bit score bins (float
//   bits [25:15], scores in (0.01,1]). Scatter reads the bin cursor first
//   and skips bins already past slot 1024; overflow detection preserved
//   (cursor only passes 1024 via real atomics, so end0>1024 <=> bad).
//   Per-bin insertion sorts give exact (score desc, anchor asc) order.
//   Legacy 11+11+10-bit radix fallback if a needed bin straddles slot 1024.
//   Phase 2 (verified structure, rescaled to 8 waves): chunked greedy NMS;
//   64x64 suppression matrix built as 8x8-column partials concurrently
//   with stride-8 kept checks + __all early break; serial resolve is
//   register/SALU only. IoU decisions bit-match the reference (same
//   operand order, division-free compare + exact-div fallback band).
//   colpart lives in sorted[512..1024) (ksel <= 400 < 512).
// ---------------------------------------------------------------------------
__global__ __launch_bounds__(K23_T, 8) void k23_topk_nms(
    const float* __restrict__ probs_t, const float* __restrict__ boxes,
    int* __restrict__ topk_anchor,
    unsigned long long* __restrict__ kept_key, int* __restrict__ kept_cnt)
{
#pragma clang fp contract(off)
  __shared__ __align__(16) int cnt[NBIN];        // 8.2 KB, reused in phase 2
  __shared__ unsigned long long sorted[1024];    // 8.2 KB (tail reused)
  __shared__ int chunk[256];                     // 1 KB
  __shared__ int res[2];
  __shared__ int s_total;
  __shared__ int s_bad;
  __shared__ int s_lcnt;
  __shared__ unsigned long long s_supm[NW];
  __shared__ int s_nk;
  const int task = blockIdx.x;
  const int tid = threadIdx.x;
  const float* sc = probs_t + (size_t)task * A_N;
  const float4* sc4 = (const float4*)sc;
  constexpr int NV4 = A_N >> 2;                  // 2183

  // ======================= Phase 1: exact top-400 =========================
  for (int i = tid; i < NBIN; i += K23_T) cnt[i] = 0;
  if (tid == 0) s_bad = 0;
  __syncthreads();

  for (int i = tid; i < NV4; i += K23_T) {
    float4 p4 = sc4[i];
    if (p4.x > 0.01f) atomicAdd(&cnt[(__float_as_uint(p4.x) >> 15) & 0x7FFu], 1);
    if (p4.y > 0.01f) atomicAdd(&cnt[(__float_as_uint(p4.y) >> 15) & 0x7FFu], 1);
    if (p4.z > 0.01f) atomicAdd(&cnt[(__float_as_uint(p4.z) >> 15) & 0x7FFu], 1);
    if (p4.w > 0.01f) atomicAdd(&cnt[(__float_as_uint(p4.w) >> 15) & 0x7FFu], 1);
  }
  __syncthreads();
  if (tid < 256) {
    int s = 0;
    for (int i = 0; i < 8; ++i) s += cnt[tid * 8 + i];
    chunk[tid] = s;
  }
  __syncthreads();
  desc_scan256(chunk, &s_total, tid);
  __syncthreads();
  if (tid < 256) {
    int acc = chunk[tid];
    for (int i = 7; i >= 0; --i) {
      int bn = tid * 8 + i;
      int h = cnt[bn];
      cnt[bn] = acc;
      acc += h;
    }
  }
  __syncthreads();
  const int total = s_total;
  const int ksel = total < K_TOP ? total : K_TOP;

  for (int i = tid; i < NV4; i += K23_T) {
    float4 p4 = sc4[i];
    const unsigned a0 = (unsigned)(i * 4);
    if (p4.x > 0.01f) {
      unsigned k = __float_as_uint(p4.x);
      int bin = (int)((k >> 15) & 0x7FFu);
      if (cnt[bin] <= 1024) {
        int pos = atomicAdd(&cnt[bin], 1);
        if (pos < 1024)
          sorted[pos] = ((unsigned long long)k << 32) | (0xFFFFFFFFu - a0);
      }
    }
    if (p4.y > 0.01f) {
      unsigned k = __float_as_uint(p4.y);
      int bin = (int)((k >> 15) & 0x7FFu);
      if (cnt[bin] <= 1024) {
        int pos = atomicAdd(&cnt[bin], 1);
        if (pos < 1024)
          sorted[pos] = ((unsigned long long)k << 32) | (0xFFFFFFFFu - (a0 + 1));
      }
    }
    if (p4.z > 0.01f) {
      unsigned k = __float_as_uint(p4.z);
      int bin = (int)((k >> 15) & 0x7FFu);
      if (cnt[bin] <= 1024) {
        int pos = atomicAdd(&cnt[bin], 1);
        if (pos < 1024)
          sorted[pos] = ((unsigned long long)k << 32) | (0xFFFFFFFFu - (a0 + 2));
      }
    }
    if (p4.w > 0.01f) {
      unsigned k = __float_as_uint(p4.w);
      int bin = (int)((k >> 15) & 0x7FFu);
      if (cnt[bin] <= 1024) {
        int pos = atomicAdd(&cnt[bin], 1);
        if (pos < 1024)
          sorted[pos] = ((unsigned long long)k << 32) | (0xFFFFFFFFu - (a0 + 3));
      }
    }
  }
  __syncthreads();
  for (int i = 0; i < 4; ++i) {                // 512 threads x 4 bins = 2048
    int bn = tid * 4 + i;
    int end0 = cnt[bn];
    int start = (bn < NBIN - 1) ? cnt[bn + 1] : 0;
    int cb = end0 - start;
    if (cb > 1 && start < K_TOP) {
      if (end0 > 1024) { s_bad = 1; continue; }   // drop requires cb>624
      for (int q = start + 1; q < end0; ++q) {
        unsigned long long v = sorted[q];
        int j = q - 1;
        while (j >= start && sorted[j] < v) { sorted[j + 1] = sorted[j]; --j; }
        sorted[j + 1] = v;
      }
    }
  }
  __syncthreads();

  if (s_bad) {
    // ------ exact legacy fallback: 11+11+10-bit radix + bitonic 1024 ------
    for (int i = tid; i < NBIN; i += K23_T) cnt[i] = 0;
    __syncthreads();
    for (int a = tid; a < A_N; a += K23_T) {
      float p = sc[a];
      if (p > 0.01f) atomicAdd(&cnt[__float_as_uint(p) >> 21], 1);
    }
    __syncthreads();
    int need = K_TOP;
    scan_select(cnt, 2048, need, tid, chunk, res);
    const unsigned b1 = (unsigned)res[0];
    const int above1 = res[1];
    const int in1 = cnt[b1];
    __syncthreads();
    unsigned cutoff;
    if (above1 + in1 <= 1024) {
      cutoff = b1 << 21;
    } else {
      need -= above1;
      for (int i = tid; i < NBIN; i += K23_T) cnt[i] = 0;
      __syncthreads();
      for (int a = tid; a < A_N; a += K23_T) {
        float p = sc[a];
        if (p > 0.01f) {
          unsigned k = __float_as_uint(p);
          if ((k >> 21) == b1) atomicAdd(&cnt[(k >> 10) & 0x7FFu], 1);
        }
      }
      __syncthreads();
      scan_select(cnt, 2048, need, tid, chunk, res);
      const unsigned b2 = (unsigned)res[0];
      need -= res[1];
      const unsigned pre22 = (b1 << 11) | b2;
      __syncthreads();
      for (int i = tid; i < 1024; i += K23_T) cnt[i] = 0;
      __syncthreads();
      for (int a = tid; a < A_N; a += K23_T) {
        float p = sc[a];
        if (p > 0.01f) {
          unsigned k = __float_as_uint(p);
          if ((k >> 10) == pre22) atomicAdd(&cnt[k & 0x3FFu], 1);
        }
      }
      __syncthreads();
      scan_select(cnt, 1024, need, tid, chunk, res);
      cutoff = (pre22 << 10) | (unsigned)res[0];
      __syncthreads();
    }
    if (tid == 0) s_lcnt = 0;
    __syncthreads();
    for (int a = tid; a < A_N; a += K23_T) {
      float p = sc[a];
      if (p > 0.01f) {
        unsigned k = __float_as_uint(p);
        if (k >= cutoff) {
          int pos = atomicAdd(&s_lcnt, 1);
          if (pos < 1024)
            sorted[pos] = ((unsigned long long)k << 32) | (unsigned)(0xFFFFFFFFu - (unsigned)a);
        }
      }
    }
    __syncthreads();
    const int n = s_lcnt < 1024 ? s_lcnt : 1024;
    const int W = (n <= 512) ? 512 : 1024;
    for (int i = tid; i < W; i += K23_T) if (i >= n) sorted[i] = 0ULL;
    __syncthreads();
    for (int kk = 2; kk <= W; kk <<= 1) {
      for (int jj = kk >> 1; jj > 0; jj >>= 1) {
        for (int i = tid; i < W; i += K23_T) {
          int ix = i ^ jj;
          if (ix > i) {
            unsigned long long va = sorted[i], vb = sorted[ix];
            bool desc = ((i & kk) == 0);
            if (desc ? (va < vb) : (va > vb)) { sorted[i] = vb; sorted[ix] = va; }
          }
        }
        __syncthreads();
      }
    }
  }

  // anchors for k5's flat->anchor lookup
  for (int r = tid; r < ksel; r += K23_T) {
    unsigned long long v = sorted[r];
    topk_anchor[(size_t)task * K_TOP + r] =
        (int)(0xFFFFFFFFu - (unsigned)(v & 0xFFFFFFFFull));
  }
  if (tid == 0) s_nk = 0;
  __syncthreads();

  // ========================= Phase 2: greedy NMS ==========================
  // overlays: kept arrays + chunk staging on dead cnt[] (8192 B region);
  // colpart on the dead tail of sorted[] (slots 512..1024; ksel <= 400).
  float4* keptb  = (float4*)cnt;                              // [0, 3200)
  float*  kepta  = (float*)(cnt + 800);                       // [3200, 4000)
  int*    keptr  = cnt + 1000;                                // [4000, 4800)
  float4* chunkb = (float4*)(cnt + 1200);                     // [4800, 5824)
  unsigned long long* colpart = &sorted[512];                 // 512 u64

  const int wid  = tid >> 6;
  const int lane = tid & 63;
  const int b = task / FG_N;
  const int c = task - b * FG_N;
  const float off = (float)(c + 1) * 302.0f;
  const float* bx = boxes + (size_t)b * (A_N * 4);

  float4 nxt = make_float4(0.0f, 0.0f, 0.0f, 0.0f);
  if (lane < ksel) {
    int a0 = (int)(0xFFFFFFFFu - (unsigned)(sorted[lane] & 0xFFFFFFFFull));
    nxt = *(const float4*)(bx + (size_t)a0 * 4);
  }
  for (int c0 = 0; c0 < ksel; c0 += 64) {
    float4 cur = nxt;                           // identical across waves
    int nidx = c0 + 64 + lane;
    if (nidx < ksel) {
      int an = (int)(0xFFFFFFFFu - (unsigned)(sorted[nidx] & 0xFFFFFFFFull));
      nxt = *(const float4*)(bx + (size_t)an * 4);
    }
    const int rem = ksel - c0;                  // >= 1
    cur.x += off; cur.y += off; cur.z += off; cur.w += off;
    const float area = (cur.z - cur.x) * (cur.w - cur.y);
    const int nk = s_nk;                        // stable since last barrier

    // (a) within-chunk suppression-matrix partial: wave w covers
    //     j in [8w, min(8w+8, jn)). Every wave stages chunkb redundantly
    //     (identical values; same-wave DS ordering makes reads safe).
    chunkb[lane] = cur;
    unsigned long long part = 0ULL;
    {
      const int jn = rem < 64 ? rem : 64;
      const int j0 = wid << 3;
      int j1 = j0 + 8; if (j1 > jn) j1 = jn;
      for (int j = j0; j < j1; ++j) {
        float4 bj = chunkb[j];                  // LDS broadcast
        float ja = (bj.z - bj.x) * (bj.w - bj.y);   // bit-equal to lane j's area
        float ix1 = fmaxf(bj.x, cur.x);
        float iy1 = fmaxf(bj.y, cur.y);
        float ix2 = fminf(bj.z, cur.z);
        float iy2 = fminf(bj.w, cur.w);
        float inter = fmaxf(ix2 - ix1, 0.0f) * fmaxf(iy2 - iy1, 0.0f);
        float denom = ja + area - inter + 1e-9f;
        float thr = 0.45f * denom;
        bool s_sup = inter > thr;
        bool amb = fabsf(inter - thr) <= 1.5e-6f * thr;
        if (amb) s_sup = (inter / denom) > 0.45f;   // exact-band fallback
        if (s_sup && j != lane) part |= 1ULL << j;
      }
    }
    colpart[(wid << 6) | lane] = part;

    // (b) candidate-vs-kept suppression, stride-NW over all waves
    bool sup = false;
    for (int k = wid; k < nk; k += NW) {
      if (__all(sup)) break;
      float4 kb = keptb[k];
      float  ka = kepta[k];
      float ix1 = fmaxf(cur.x, kb.x);
      float iy1 = fmaxf(cur.y, kb.y);
      float ix2 = fminf(cur.z, kb.z);
      float iy2 = fminf(cur.w, kb.w);
      float inter = fmaxf(ix2 - ix1, 0.0f) * fmaxf(iy2 - iy1, 0.0f);
      float denom = ka + area - inter + 1e-9f;
      float thr = 0.45f * denom;
      bool s_sup = inter > thr;
      bool amb = fabsf(inter - thr) <= 1.5e-6f * thr;
      if (amb) s_sup = (inter / denom) > 0.45f;     // exact-band fallback
      sup = sup || s_sup;
    }
    s_supm[wid] = __ballot(sup);
    __syncthreads();

    if (wid == 0) {
      unsigned long long col =
          colpart[lane]        | colpart[64  | lane] |
          colpart[128 | lane]  | colpart[192 | lane] |
          colpart[256 | lane]  | colpart[320 | lane] |
          colpart[384 | lane]  | colpart[448 | lane];
      const unsigned long long vmask =
          (rem >= 64) ? ~0ULL : ((1ULL << rem) - 1ULL);
      unsigned long long todo =
          vmask & ~(s_supm[0] | s_supm[1] | s_supm[2] | s_supm[3] |
                    s_supm[4] | s_supm[5] | s_supm[6] | s_supm[7]);
      unsigned long long surv = 0ULL;
      int ns = 0;
      const int room = D_N - nk;
      // serial greedy resolve: register/SALU only, no LDS, no IoU
      while (todo) {
        if (ns == room) break;
        int j = __ffsll((unsigned long long)todo) - 1;
        surv |= 1ULL << j;
        ++ns;
        todo &= ~(1ULL << j);
        bool msup = (col >> j) & 1ULL;
        unsigned long long supj = __ballot(msup);
        todo &= ~supj;
      }
      if ((surv >> lane) & 1ULL) {
        int my = nk + __popcll(surv & ((1ULL << lane) - 1ULL));
        keptb[my] = cur;
        kepta[my] = area;
        keptr[my] = c0 + lane;
      }
      if (lane == 0) s_nk = nk + ns;
    }
    __syncthreads();
    if (s_nk >= D_N) break;
  }

  const int nkf = s_nk;
  for (int k = tid; k < nkf; k += K23_T) {
    int r = keptr[k];
    unsigned sb = (unsigned)(sorted[r] >> 32);
    kept_key[(size_t)task * D_N + k] =
        ((unsigned long long)sb << 32) |
        (unsigned)(0xFFFFFFFFu - (unsigned)(c * K_TOP + r));
  }
  if (tid == 0) kept_cnt[task] = nkf;
}

// ---------------------------------------------------------------------------
// K4: per-image top-200 of survivor keys via histogram rank-scatter.
//     Score bits live in u64 key bits [57:46] -> monotone 12-bit bin
//     (scores in (0.01,1]). 1024 threads/block. Histogram + wave-parallel
//     descending prefix + scatter + per-bin insertion sorts (4 bins/thread).
//     Legacy radix+bitonic fallback if a needed bin straddles slot 1024.
// ---------------------------------------------------------------------------
__global__ __launch_bounds__(K4_T) void k4_sel(
    const unsigned long long* __restrict__ kept_key,
    const int* __restrict__ kept_cnt, int* __restrict__ pick_flat)
{
  __shared__ __align__(16) int hist[4096];
  __shared__ unsigned long long sorted[1024];
  __shared__ int chunk[256];
  __shared__ int res[2];
  __shared__ int s_total;
  __shared__ int s_bad;
  __shared__ int s_lcnt;
  __shared__ int s_cnts[FG_N];
  const int b = blockIdx.x;
  const int tid = threadIdx.x;
  const unsigned long long* kb = kept_key + (size_t)b * FG_N * D_N;

  if (tid < FG_N) s_cnts[tid] = kept_cnt[b * FG_N + tid];
  for (int i = tid; i < 4096; i += K4_T) hist[i] = 0;
  if (tid == 0) s_bad = 0;
  __syncthreads();

  for (int idx = tid; idx < FG_N * D_N; idx += K4_T) {
    int c = idx / D_N, r = idx - c * D_N;
    if (r < s_cnts[c])
      atomicAdd(&hist[(int)((kb[idx] >> 46) & 0xFFFull)], 1);
  }
  __syncthreads();
  if (tid < 256) {
    int s = 0;
    for (int i = 0; i < 16; ++i) s += hist[tid * 16 + i];
    chunk[tid] = s;
  }
  __syncthreads();
  desc_scan256(chunk, &s_total, tid);
  __syncthreads();
  if (tid < 256) {
    int acc = chunk[tid];
    for (int i = 15; i >= 0; --i) {
      int bn = tid * 16 + i;
      int h = hist[bn];
      hist[bn] = acc;
      acc += h;
    }
  }
  __syncthreads();
  const int total = s_total;
  const int npick = total < D_N ? total : D_N;

  for (int idx = tid; idx < FG_N * D_N; idx += K4_T) {
    int c = idx / D_N, r = idx - c * D_N;
    if (r < s_cnts[c]) {
      unsigned long long k = kb[idx];
      int pos = atomicAdd(&hist[(int)((k >> 46) & 0xFFFull)], 1);
      if (pos < 1024) sorted[pos] = k;
    }
  }
  __syncthreads();
  for (int i = 0; i < 4; ++i) {
    int bn = tid * 4 + i;
    int end0 = hist[bn];
    int start = (bn < 4095) ? hist[bn + 1] : 0;
    int cb = end0 - start;
    if (cb > 1 && start < D_N) {
      if (end0 > 1024) { s_bad = 1; continue; }   // drop requires cb>824
      for (int q = start + 1; q < end0; ++q) {
        unsigned long long v = sorted[q];
        int j = q - 1;
        while (j >= start && sorted[j] < v) { sorted[j + 1] = sorted[j]; --j; }
        sorted[j + 1] = v;
      }
    }
  }
  __syncthreads();

  if (s_bad) {
    // ---------- exact legacy fallback: radix select + bitonic 1024 --------
    for (int i = tid; i < 4096; i += K4_T) hist[i] = 0;
    if (tid == 0) s_lcnt = 0;
    __syncthreads();
    for (int idx = tid; idx < FG_N * D_N; idx += K4_T) {
      int c = idx / D_N, r = idx - c * D_N;
      if (r < s_cnts[c]) {
        unsigned long long k = kb[idx];
        atomicAdd(&hist[(int)(k >> 52)], 1);
      }
    }
    __syncthreads();
    unsigned cutoff32 = 1u;
    if (total > D_N) {
      int need = D_N;
      scan_select(hist, 4096, need, tid, chunk, res);
      const unsigned b1 = (unsigned)res[0];
      const int above1 = res[1];
      const int in1 = hist[b1];
      __syncthreads();
      if (above1 + in1 <= 1024) {
        cutoff32 = b1 << 20;
      } else {
        need -= above1;
        for (int i = tid; i < 4096; i += K4_T) hist[i] = 0;
        __syncthreads();
        for (int idx = tid; idx < FG_N * D_N; idx += K4_T) {
          int c = idx / D_N, r = idx - c * D_N;
          if (r < s_cnts[c]) {
            unsigned long long k = kb[idx];
            if ((unsigned)(k >> 52) == b1)
              atomicAdd(&hist[(int)((k >> 40) & 0xFFFull)], 1);
          }
        }
        __syncthreads();
        scan_select(hist, 4096, need, tid, chunk, res);
        const unsigned b2 = (unsigned)res[0];
        need -= res[1];
        const unsigned pre12 = (b1 << 12) | b2;
        __syncthreads();
        if (tid < 256) hist[tid] = 0;
        __syncthreads();
        for (int idx = tid; idx < FG_N * D_N; idx += K4_T) {
          int c = idx / D_N, r = idx - c * D_N;
          if (r < s_cnts[c]) {
            unsigned long long k = kb[idx];
            if ((unsigned)(k >> 40) == pre12)
              atomicAdd(&hist[(int)((k >> 32) & 0xFFull)], 1);
          }
        }
        __syncthreads();
        scan_select(hist, 256, need, tid, chunk, res);
        cutoff32 = (pre12 << 8) | (unsigned)res[0];
        __syncthreads();
      }
    }
    const unsigned long long cutkey = (unsigned long long)cutoff32 << 32;
    for (int idx = tid; idx < FG_N * D_N; idx += K4_T) {
      int c = idx / D_N, r = idx - c * D_N;
      if (r < s_cnts[c]) {
        unsigned long long k = kb[idx];
        if (k >= cutkey) {
          int pos = atomicAdd(&s_lcnt, 1);
          if (pos < 1024) sorted[pos] = k;
        }
      }
    }
    __syncthreads();
    const int n = s_lcnt < 1024 ? s_lcnt : 1024;
    const int W = (n <= 256) ? 256 : (n <= 512) ? 512 : 1024;
    for (int i = tid; i < W; i += K4_T) if (i >= n) sorted[i] = 0ULL;
    __syncthreads();
    for (int kk = 2; kk <= W; kk <<= 1) {
      for (int jj = kk >> 1; jj > 0; jj >>= 1) {
        for (int i = tid; i < W; i += K4_T) {
          int ix = i ^ jj;
          if (ix > i) {
            unsigned long long va = sorted[i], vb = sorted[ix];
            bool desc = ((i & kk) == 0);
            if (desc ? (va < vb) : (va > vb)) { sorted[i] = vb; sorted[ix] = va; }
          }
        }
        __syncthreads();
      }
    }
  }

  for (int i = tid; i < D_N; i += K4_T) {
    int v = -1;
    if (i < npick)
      v = (int)(0xFFFFFFFFu - (unsigned)(sorted[i] & 0xFFFFFFFFull));
    pick_flat[b * D_N + i] = v;
  }
}

// ---------------------------------------------------------------------------
// K5: one wave per pick; packed u64 butterfly top-2 over 90 classes.
// ---------------------------------------------------------------------------
__global__ __launch_bounds__(256) void k5_out(
    const float* __restrict__ probs_t, const float* __restrict__ boxes,
    const int* __restrict__ topk_anchor, const int* __restrict__ pick_flat,
    float* __restrict__ out)
{
  const int wid  = threadIdx.x >> 6;
  const int lane = threadIdx.x & 63;
  const int pick = blockIdx.x * 4 + wid;
  const int b = pick / D_N;
  float* ob = out + (size_t)pick * 4;
  float* os = out + (size_t)B_N * D_N * 4 + (size_t)pick * 2;
  float* ol = out + (size_t)B_N * D_N * 6 + (size_t)pick * 2;
  const int flat = pick_flat[pick];
  if (flat < 0) {
    if (lane == 0) {
      ob[0] = 0.0f; ob[1] = 0.0f; ob[2] = 0.0f; ob[3] = 0.0f;
      os[0] = 0.0f; os[1] = 0.0f;
      ol[0] = 0.0f; ol[1] = 0.0f;
    }
    return;
  }
  const int c = flat / K_TOP;
  const int r = flat - c * K_TOP;
  const int anchor = topk_anchor[((size_t)b * FG_N + c) * K_TOP + r];
  const float* pp = probs_t + (size_t)b * FG_N * A_N + anchor;

  unsigned long long hi, lo = 0ULL;
  {
    float p = pp[(size_t)lane * A_N];
    hi = ((unsigned long long)__float_as_uint(p) << 32) | (0xFFFFFFFFu - (unsigned)lane);
  }
  if (lane + 64 < FG_N) {
    float p = pp[(size_t)(lane + 64) * A_N];
    unsigned long long k2 = ((unsigned long long)__float_as_uint(p) << 32) |
                            (0xFFFFFFFFu - (unsigned)(lane + 64));
    if (k2 > hi) { lo = hi; hi = k2; } else lo = k2;
  }
#pragma unroll
  for (int d = 1; d < 64; d <<= 1) {
    unsigned long long oh = __shfl_xor(hi, d, 64);
    unsigned long long ol2 = __shfl_xor(lo, d, 64);
    unsigned long long nh = hi > oh ? hi : oh;
    unsigned long long mn = hi > oh ? oh : hi;
    unsigned long long ml = lo > ol2 ? lo : ol2;
    hi = nh;
    lo = mn > ml ? mn : ml;
  }
  if (lane == 0) {
    float4 bp = *(const float4*)(boxes + ((size_t)b * A_N + anchor) * 4);
    *(float4*)ob = bp;
    unsigned cc1 = 0xFFFFFFFFu - (unsigned)(hi & 0xFFFFFFFFull);
    unsigned cc2 = 0xFFFFFFFFu - (unsigned)(lo & 0xFFFFFFFFull);
    os[0] = __uint_as_float((unsigned)(hi >> 32));
    os[1] = __uint_as_float((unsigned)(lo >> 32));
    ol[0] = (float)(cc1 + 1);
    ol[1] = (float)(cc2 + 1);
  }
}

// ---------------------------------------------------------------------------
extern "C" void kernel_launch(void* const* d_in, const int* in_sizes, int n_in,
                              void* d_out, int out_size, void* d_ws, size_t ws_size,
                              hipStream_t stream)
{
  (void)in_sizes; (void)n_in; (void)out_size; (void)ws_size;
  const float* cls = (const float*)d_in[0];
  const float* reg = (const float*)d_in[1];
  const float* anc = (const float*)d_in[2];

  char* w = (char*)d_ws;
  size_t off = 0;
  auto carve = [&](size_t bytes) -> char* {
    char* p = w + off;
    off += (bytes + 255) & ~(size_t)255;
    return p;
  };
  float* probs_t                = (float*)carve((size_t)B_N * FG_N * A_N * 4);
  float* boxes                  = (float*)carve((size_t)B_N * A_N * 4 * 4);
  int* topk_anchor              = (int*)carve((size_t)NTASK * K_TOP * 4);
  unsigned long long* kept_key  = (unsigned long long*)carve((size_t)NTASK * D_N * 8);
  int* kept_cnt                 = (int*)carve((size_t)NTASK * 4);
  int* pick_flat                = (int*)carve((size_t)B_N * D_N * 4);

  hipLaunchKernelGGL(k1_softmax_decode, dim3((B_N * A_N) / K1_ANB), dim3(K1B_T), 0, stream,
                     cls, reg, anc, probs_t, boxes);
  hipLaunchKernelGGL(k23_topk_nms, dim3(NTASK), dim3(K23_T), 0, stream,
                     probs_t, boxes, topk_anchor, kept_key, kept_cnt);
  hipLaunchKernelGGL(k4_sel, dim3(B_N), dim3(K4_T), 0, stream,
                     kept_key, kept_cnt, pick_flat);
  hipLaunchKernelGGL(k5_out, dim3(B_N * D_N / 4), dim3(256), 0, stream,
                     probs_t, boxes, topk_anchor, pick_flat, (float*)d_out);
}

// Round 10
// 228.833 us; speedup vs baseline: 1.0643x; 1.0643x over previous
//
#include <hip/hip_runtime.h>
#include <cstdint>
#include <cstddef>

#define B_N   16
#define A_N   8732
#define C_N   91
#define FG_N  90
#define K_TOP 400
#define D_N   200
#define NTASK (B_N * FG_N)   // 1440
#define K4_T  1024           // k4 threads (16 blocks is latency-bound)
#define NBIN  2048           // k23 histogram bins (8 KB)
#define K1B_T 512            // k1 threads
#define K1_ANB 64            // anchors per k1 block; 139712/64 = 2183 exact

// ---------------------------------------------------------------------------
// K1: softmax + decode. Coalesced LDS staging + register/shfl softmax
//   (bit-exact, verified absmax=0.0) + coalesced float4 write-out.
//   64 anchors x 512 threads (verified R7/R8).
// ---------------------------------------------------------------------------
__global__ __launch_bounds__(K1B_T) void k1_softmax_decode(
    const float* __restrict__ cls, const float* __restrict__ reg,
    const float* __restrict__ anc, float* __restrict__ probs_t,
    float* __restrict__ boxes)
{
#pragma clang fp contract(off)
  __shared__ __align__(16) float lds[K1_ANB * C_N];   // 5824 floats = 23296 B
  const int tid = threadIdx.x;
  const int gi0 = blockIdx.x * K1_ANB;

  // stage-in: block slab = 64 anchors x 91 classes, contiguous in (b,a,c)
  {
    const float4* src = (const float4*)cls + ((size_t)gi0 * C_N >> 2);
    float4* dst = (float4*)lds;
    constexpr int NF4 = (K1_ANB * C_N) / 4;           // 1456
    for (int t = tid; t < NF4; t += K1B_T) dst[t] = src[t];
  }
  __syncthreads();

  const int g  = tid >> 3;                     // local anchor 0..63
  const int l8 = tid & 7;                      // class segment 0..7
  const int gi = gi0 + g;
  const int b  = gi / A_N;
  const int a  = gi - b * A_N;
  const int c0 = l8 * 12;
  const float* lg = lds + g * C_N;

  float v[12];
#pragma unroll
  for (int i = 0; i < 12; ++i) {
    int c = c0 + i;
    v[i] = (c < C_N) ? lg[c] : -__builtin_huge_valf();
  }
  float m = v[0];
#pragma unroll
  for (int i = 1; i < 12; ++i) m = fmaxf(m, v[i]);
#pragma unroll
  for (int d = 1; d < 8; d <<= 1) m = fmaxf(m, __shfl_xor(m, d, 64));

  float e[12];
  float s = 0.0f;
#pragma unroll
  for (int i = 0; i < 12; ++i) {               // exp(-inf)=0; s+0.0f==s
    e[i] = expf(v[i] - m);
    s += e[i];
  }
#pragma unroll
  for (int d = 1; d < 8; d <<= 1) s += __shfl_xor(s, d, 64);

  // probs back into LDS (thread-private slots; overwrite logits)
#pragma unroll
  for (int i = 0; i < 12; ++i) {
    int c = c0 + i;
    if (c < C_N) lds[g * C_N + c] = e[i] / s;
  }

  // decode on the 7-class lane (registers/global only; no LDS hazard)
  if (l8 == 7) {
    float4 rl = *(const float4*)(reg + (size_t)gi * 4);
    float4 an = *(const float4*)(anc + (size_t)a * 4);
    float wa = an.z - an.x;
    float ha = an.w - an.y;
    float cxa = an.x + 0.5f * wa;
    float cya = an.y + 0.5f * ha;
    float dx = rl.x / 10.0f;
    float dy = rl.y / 10.0f;
    const float clipv = 4.135166556742356f;   // log(1000/16)
    float dw = fminf(rl.z / 5.0f, clipv);
    float dh = fminf(rl.w / 5.0f, clipv);
    float t1 = dx * wa;  float cx = t1 + cxa;
    float t2 = dy * ha;  float cy = t2 + cya;
    float w = expf(dw) * wa;
    float h = expf(dh) * ha;
    float4 out;
    out.x = fminf(fmaxf(cx - 0.5f * w, 0.0f), 300.0f);
    out.y = fminf(fmaxf(cy - 0.5f * h, 0.0f), 300.0f);
    out.z = fminf(fmaxf(cx + 0.5f * w, 0.0f), 300.0f);
    out.w = fminf(fmaxf(cy + 0.5f * h, 0.0f), 300.0f);
    *(float4*)(boxes + (size_t)gi * 4) = out;
  }
  __syncthreads();

  // coalesced write-out: 90 rows x 16 anchor-quads = 1440 float4 units
  constexpr int NU = FG_N * (K1_ANB / 4);      // 1440
  for (int u = tid; u < NU; u += K1B_T) {
    int r  = u >> 4;                           // fg row (class r+1)
    int q  = u & 15;                           // anchor quad
    int la = q << 2;
    int gja = gi0 + la;
    int b0 = gja / A_N;
    int b3 = (gja + 3) / A_N;
    float4 val;
    val.x = lds[(la + 0) * C_N + r + 1];
    val.y = lds[(la + 1) * C_N + r + 1];
    val.z = lds[(la + 2) * C_N + r + 1];
    val.w = lds[(la + 3) * C_N + r + 1];
    if (b0 == b3) {
      int a0 = gja - b0 * A_N;
      *(float4*)(probs_t + ((size_t)b0 * FG_N + r) * A_N + a0) = val;
    } else {                                   // image-boundary quad
      float tmp[4] = {val.x, val.y, val.z, val.w};
#pragma unroll
      for (int k = 0; k < 4; ++k) {
        int gj = gja + k;
        int bk = gj / A_N;
        int ak = gj - bk * A_N;
        probs_t[((size_t)bk * FG_N + r) * A_N + ak] = tmp[k];
      }
    }
  }
}

// ---------------------------------------------------------------------------
// shared helper: descending rank-select over a 256-chunked histogram.
// Thread-count-safe: threads >=256 skip compute but hit every barrier.
// nbins must be a multiple of 256 (per = nbins/256 bins per thread).
// (only used on the rare exact-fallback paths)
// ---------------------------------------------------------------------------
__device__ __forceinline__ void scan_select(int* hist, int nbins, int need,
                                            int tid, int* chunk, int* res)
{
  int per = nbins >> 8;            // 2048 -> 8, 1024 -> 4, 256 -> 1
  if (tid < 256) {
    int s = 0;
    for (int i = 0; i < per; ++i) s += hist[tid * per + i];
    chunk[tid] = s;
  }
  __syncthreads();
  if (tid == 0) {
    int cum = 0;
    for (int t2 = 255; t2 >= 0; --t2) { int v = chunk[t2]; chunk[t2] = cum; cum += v; }
  }
  __syncthreads();
  if (tid < 256) {
    int cum = chunk[tid];          // count in strictly-higher chunks
    for (int i = per - 1; i >= 0; --i) {
      int bn = tid * per + i;
      int h = hist[bn];
      if (cum < need && need <= cum + h) { res[0] = bn; res[1] = cum; }
      cum += h;
    }
  }
  __syncthreads();
}

// ---------------------------------------------------------------------------
// parallel descending exclusive scan over chunk[256], done by wave 0 alone.
// chunk[t] <- sum_{t' > t} chunk_in[t'];  *s_total <- sum_all.
// Caller must barrier before (chunk populated) and after (results visible).
// ---------------------------------------------------------------------------
__device__ __forceinline__ void desc_scan256(int* chunk, int* s_total, int tid)
{
  if (tid < 64) {
    const int l = tid;
    int e0 = chunk[4 * l + 0];
    int e1 = chunk[4 * l + 1];
    int e2 = chunk[4 * l + 2];
    int e3 = chunk[4 * l + 3];
    int ls = e0 + e1 + e2 + e3;
    int suf = ls;
#pragma unroll
    for (int d = 1; d < 64; d <<= 1) {
      int o = __shfl(suf, l + d, 64);
      if (l + d < 64) suf += o;
    }
    int excl = suf - ls;                 // sum over lanes strictly above
    chunk[4 * l + 3] = excl;
    chunk[4 * l + 2] = excl + e3;
    chunk[4 * l + 1] = excl + e3 + e2;
    chunk[4 * l + 0] = excl + e3 + e2 + e1;
    if (l == 0) *s_total = suf;
  }
}

// ---------------------------------------------------------------------------
// K23: FUSED top-400 + NMS, one block (4 waves = 1 per SIMD, 256 threads)
// per (image, fg-class). R9's 512t variant regressed (-14%): occupancy
// rose 47->61 but VALUBusy stayed flat -- the kernel is dependency-bound
// (barriers + LDS atomics), not slot-starved, and 4-blocks/CU residency
// created a 416-block half-empty second scheduling round. 256t all-resident
// (R8 config, 113.4us) restored exactly.
//   NEW: XCD-aware bijective task swizzle (1440 = 8 x 180): each XCD gets
//   a contiguous 180-task chunk = 2 images, so phase-2's scattered box
//   reads hit a 1.1MB L2-resident boxes slice instead of thrashing all
//   16 images (9MB > 4MB per-XCD L2).
//   Phase 1: histogram rank-scatter over monotone 11-bit score bins (float
//   bits [25:15], scores in (0.01,1]); register-cached score row across
//   both passes; cursor-skip on bins already past slot 1024 (overflow
//   detection preserved: cursor only passes 1024 via real atomics, so
//   end0>1024 <=> bad). Per-bin insertion sorts give exact (score desc,
//   anchor asc) order. Legacy 11+11+10-bit radix fallback if a needed bin
//   straddles slot 1024.
//   Phase 2 (verified): chunked greedy NMS; 64x64 suppression matrix built
//   as 4x16-column partials concurrently with stride-4 kept checks + __all
//   early break; serial resolve is register/SALU only. IoU decisions
//   bit-match the reference (same operand order, division-free compare +
//   exact-div fallback band). colpart lives in sorted[640..896) (ksel<=400).
// ---------------------------------------------------------------------------
__global__ __launch_bounds__(256) void k23_topk_nms(
    const float* __restrict__ probs_t, const float* __restrict__ boxes,
    int* __restrict__ topk_anchor,
    unsigned long long* __restrict__ kept_key, int* __restrict__ kept_cnt)
{
#pragma clang fp contract(off)
  __shared__ __align__(16) int cnt[NBIN];        // 8.2 KB, reused in phase 2
  __shared__ unsigned long long sorted[1024];    // 8.2 KB (tail reused)
  __shared__ int chunk[256];                     // 1 KB
  __shared__ int res[2];
  __shared__ int s_total;
  __shared__ int s_bad;
  __shared__ int s_lcnt;
  __shared__ unsigned long long s_supm[4];
  __shared__ int s_nk;
  // bijective XCD swizzle: 1440 = 8 * 180 exactly
  const int task = (blockIdx.x & 7) * (NTASK / 8) + (blockIdx.x >> 3);
  const int tid = threadIdx.x;
  const float* sc = probs_t + (size_t)task * A_N;
  const float4* sc4 = (const float4*)sc;
  constexpr int NV4 = A_N >> 2;                  // 2183
  constexpr int NJ = (NV4 + 255) / 256;          // 9 float4 per thread

  // ======================= Phase 1: exact top-400 =========================
  for (int i = tid; i < NBIN; i += 256) cnt[i] = 0;
  if (tid == 0) s_bad = 0;
  __syncthreads();

  float4 c4[NJ];                                 // register-cached score row
#pragma unroll
  for (int j = 0; j < NJ; ++j) {
    int i = tid + j * 256;
    if (i < NV4) {
      float4 p4 = sc4[i];
      c4[j] = p4;
      if (p4.x > 0.01f) atomicAdd(&cnt[(__float_as_uint(p4.x) >> 15) & 0x7FFu], 1);
      if (p4.y > 0.01f) atomicAdd(&cnt[(__float_as_uint(p4.y) >> 15) & 0x7FFu], 1);
      if (p4.z > 0.01f) atomicAdd(&cnt[(__float_as_uint(p4.z) >> 15) & 0x7FFu], 1);
      if (p4.w > 0.01f) atomicAdd(&cnt[(__float_as_uint(p4.w) >> 15) & 0x7FFu], 1);
    }
  }
  __syncthreads();
  {
    int s = 0;
    for (int i = 0; i < 8; ++i) s += cnt[tid * 8 + i];
    chunk[tid] = s;
  }
  __syncthreads();
  desc_scan256(chunk, &s_total, tid);
  __syncthreads();
  {
    int acc = chunk[tid];
    for (int i = 7; i >= 0; --i) {
      int bn = tid * 8 + i;
      int h = cnt[bn];
      cnt[bn] = acc;
      acc += h;
    }
  }
  __syncthreads();
  const int total = s_total;
  const int ksel = total < K_TOP ? total : K_TOP;

#pragma unroll
  for (int j = 0; j < NJ; ++j) {
    int i = tid + j * 256;
    if (i < NV4) {
      float4 p4 = c4[j];
      const unsigned a0 = (unsigned)(i * 4);
      if (p4.x > 0.01f) {
        unsigned k = __float_as_uint(p4.x);
        int bin = (int)((k >> 15) & 0x7FFu);
        if (cnt[bin] <= 1024) {
          int pos = atomicAdd(&cnt[bin], 1);
          if (pos < 1024)
            sorted[pos] = ((unsigned long long)k << 32) | (0xFFFFFFFFu - a0);
        }
      }
      if (p4.y > 0.01f) {
        unsigned k = __float_as_uint(p4.y);
        int bin = (int)((k >> 15) & 0x7FFu);
        if (cnt[bin] <= 1024) {
          int pos = atomicAdd(&cnt[bin], 1);
          if (pos < 1024)
            sorted[pos] = ((unsigned long long)k << 32) | (0xFFFFFFFFu - (a0 + 1));
        }
      }
      if (p4.z > 0.01f) {
        unsigned k = __float_as_uint(p4.z);
        int bin = (int)((k >> 15) & 0x7FFu);
        if (cnt[bin] <= 1024) {
          int pos = atomicAdd(&cnt[bin], 1);
          if (pos < 1024)
            sorted[pos] = ((unsigned long long)k << 32) | (0xFFFFFFFFu - (a0 + 2));
        }
      }
      if (p4.w > 0.01f) {
        unsigned k = __float_as_uint(p4.w);
        int bin = (int)((k >> 15) & 0x7FFu);
        if (cnt[bin] <= 1024) {
          int pos = atomicAdd(&cnt[bin], 1);
          if (pos < 1024)
            sorted[pos] = ((unsigned long long)k << 32) | (0xFFFFFFFFu - (a0 + 3));
        }
      }
    }
  }
  __syncthreads();
  for (int i = 0; i < 8; ++i) {
    int bn = tid * 8 + i;
    int end0 = cnt[bn];
    int start = (bn < NBIN - 1) ? cnt[bn + 1] : 0;
    int cb = end0 - start;
    if (cb > 1 && start < K_TOP) {
      if (end0 > 1024) { s_bad = 1; continue; }   // drop requires cb>624
      for (int q = start + 1; q < end0; ++q) {
        unsigned long long v = sorted[q];
        int j = q - 1;
        while (j >= start && sorted[j] < v) { sorted[j + 1] = sorted[j]; --j; }
        sorted[j + 1] = v;
      }
    }
  }
  __syncthreads();

  if (s_bad) {
    // ------ exact legacy fallback: 11+11+10-bit radix + bitonic 1024 ------
    for (int i = tid; i < NBIN; i += 256) cnt[i] = 0;
    __syncthreads();
    for (int a = tid; a < A_N; a += 256) {
      float p = sc[a];
      if (p > 0.01f) atomicAdd(&cnt[__float_as_uint(p) >> 21], 1);
    }
    __syncthreads();
    int need = K_TOP;
    scan_select(cnt, 2048, need, tid, chunk, res);
    const unsigned b1 = (unsigned)res[0];
    const int above1 = res[1];
    const int in1 = cnt[b1];
    __syncthreads();
    unsigned cutoff;
    if (above1 + in1 <= 1024) {
      cutoff = b1 << 21;
    } else {
      need -= above1;
      for (int i = tid; i < NBIN; i += 256) cnt[i] = 0;
      __syncthreads();
      for (int a = tid; a < A_N; a += 256) {
        float p = sc[a];
        if (p > 0.01f) {
          unsigned k = __float_as_uint(p);
          if ((k >> 21) == b1) atomicAdd(&cnt[(k >> 10) & 0x7FFu], 1);
        }
      }
      __syncthreads();
      scan_select(cnt, 2048, need, tid, chunk, res);
      const unsigned b2 = (unsigned)res[0];
      need -= res[1];
      const unsigned pre22 = (b1 << 11) | b2;
      __syncthreads();
      for (int i = tid; i < 1024; i += 256) cnt[i] = 0;
      __syncthreads();
      for (int a = tid; a < A_N; a += 256) {
        float p = sc[a];
        if (p > 0.01f) {
          unsigned k = __float_as_uint(p);
          if ((k >> 10) == pre22) atomicAdd(&cnt[k & 0x3FFu], 1);
        }
      }
      __syncthreads();
      scan_select(cnt, 1024, need, tid, chunk, res);
      cutoff = (pre22 << 10) | (unsigned)res[0];
      __syncthreads();
    }
    if (tid == 0) s_lcnt = 0;
    __syncthreads();
    for (int a = tid; a < A_N; a += 256) {
      float p = sc[a];
      if (p > 0.01f) {
        unsigned k = __float_as_uint(p);
        if (k >= cutoff) {
          int pos = atomicAdd(&s_lcnt, 1);
          if (pos < 1024)
            sorted[pos] = ((unsigned long long)k << 32) | (unsigned)(0xFFFFFFFFu - (unsigned)a);
        }
      }
    }
    __syncthreads();
    const int n = s_lcnt < 1024 ? s_lcnt : 1024;
    const int W = (n <= 512) ? 512 : 1024;
    for (int i = tid; i < W; i += 256) if (i >= n) sorted[i] = 0ULL;
    __syncthreads();
    for (int kk = 2; kk <= W; kk <<= 1) {
      for (int jj = kk >> 1; jj > 0; jj >>= 1) {
        for (int i = tid; i < W; i += 256) {
          int ix = i ^ jj;
          if (ix > i) {
            unsigned long long va = sorted[i], vb = sorted[ix];
            bool desc = ((i & kk) == 0);
            if (desc ? (va < vb) : (va > vb)) { sorted[i] = vb; sorted[ix] = va; }
          }
        }
        __syncthreads();
      }
    }
  }

  // anchors for k5's flat->anchor lookup
  for (int r = tid; r < ksel; r += 256) {
    unsigned long long v = sorted[r];
    topk_anchor[(size_t)task * K_TOP + r] =
        (int)(0xFFFFFFFFu - (unsigned)(v & 0xFFFFFFFFull));
  }
  if (tid == 0) s_nk = 0;
  __syncthreads();

  // ========================= Phase 2: greedy NMS ==========================
  // overlays: kept arrays + chunk staging on dead cnt[] (8192 B region);
  // colpart on the dead tail of sorted[] (slots 640..896; ksel <= 400).
  float4* keptb  = (float4*)cnt;                              // [0, 3200)
  float*  kepta  = (float*)(cnt + 800);                       // [3200, 4000)
  int*    keptr  = cnt + 1000;                                // [4000, 4800)
  float4* chunkb = (float4*)(cnt + 1200);                     // [4800, 5824)
  unsigned long long* colpart = &sorted[640];                 // 256 u64

  const int wid  = tid >> 6;
  const int lane = tid & 63;
  const int b = task / FG_N;
  const int c = task - b * FG_N;
  const float off = (float)(c + 1) * 302.0f;
  const float* bx = boxes + (size_t)b * (A_N * 4);

  float4 nxt = make_float4(0.0f, 0.0f, 0.0f, 0.0f);
  if (lane < ksel) {
    int a0 = (int)(0xFFFFFFFFu - (unsigned)(sorted[lane] & 0xFFFFFFFFull));
    nxt = *(const float4*)(bx + (size_t)a0 * 4);
  }
  for (int c0 = 0; c0 < ksel; c0 += 64) {
    float4 cur = nxt;                           // identical across waves
    int nidx = c0 + 64 + lane;
    if (nidx < ksel) {
      int an = (int)(0xFFFFFFFFu - (unsigned)(sorted[nidx] & 0xFFFFFFFFull));
      nxt = *(const float4*)(bx + (size_t)an * 4);
    }
    const int rem = ksel - c0;                  // >= 1
    cur.x += off; cur.y += off; cur.z += off; cur.w += off;
    const float area = (cur.z - cur.x) * (cur.w - cur.y);
    const int nk = s_nk;                        // stable since last barrier

    // (a) within-chunk suppression-matrix partial: wave w covers
    //     j in [16w, min(16w+16, jn)). All waves stage chunkb redundantly
    //     (identical values; same-wave DS ordering makes reads safe).
    chunkb[lane] = cur;
    unsigned long long part = 0ULL;
    {
      const int jn = rem < 64 ? rem : 64;
      const int j0 = wid << 4;
      int j1 = j0 + 16; if (j1 > jn) j1 = jn;
      for (int j = j0; j < j1; ++j) {
        float4 bj = chunkb[j];                  // LDS broadcast
        float ja = (bj.z - bj.x) * (bj.w - bj.y);   // bit-equal to lane j's area
        float ix1 = fmaxf(bj.x, cur.x);
        float iy1 = fmaxf(bj.y, cur.y);
        float ix2 = fminf(bj.z, cur.z);
        float iy2 = fminf(bj.w, cur.w);
        float inter = fmaxf(ix2 - ix1, 0.0f) * fmaxf(iy2 - iy1, 0.0f);
        float denom = ja + area - inter + 1e-9f;
        float thr = 0.45f * denom;
        bool s_sup = inter > thr;
        bool amb = fabsf(inter - thr) <= 1.5e-6f * thr;
        if (amb) s_sup = (inter / denom) > 0.45f;   // exact-band fallback
        if (s_sup && j != lane) part |= 1ULL << j;
      }
    }
    colpart[(wid << 6) | lane] = part;

    // (b) candidate-vs-kept suppression, stride-4 over all waves
    bool sup = false;
    for (int k = wid; k < nk; k += 4) {
      if (__all(sup)) break;
      float4 kb = keptb[k];
      float  ka = kepta[k];
      float ix1 = fmaxf(cur.x, kb.x);
      float iy1 = fmaxf(cur.y, kb.y);
      float ix2 = fminf(cur.z, kb.z);
      float iy2 = fminf(cur.w, kb.w);
      float inter = fmaxf(ix2 - ix1, 0.0f) * fmaxf(iy2 - iy1, 0.0f);
      float denom = ka + area - inter + 1e-9f;
      float thr = 0.45f * denom;
      bool s_sup = inter > thr;
      bool amb = fabsf(inter - thr) <= 1.5e-6f * thr;
      if (amb) s_sup = (inter / denom) > 0.45f;     // exact-band fallback
      sup = sup || s_sup;
    }
    s_supm[wid] = __ballot(sup);
    __syncthreads();

    if (wid == 0) {
      unsigned long long col = colpart[lane] | colpart[64 | lane] |
                               colpart[128 | lane] | colpart[192 | lane];
      const unsigned long long vmask =
          (rem >= 64) ? ~0ULL : ((1ULL << rem) - 1ULL);
      unsigned long long todo =
          vmask & ~(s_supm[0] | s_supm[1] | s_supm[2] | s_supm[3]);
      unsigned long long surv = 0ULL;
      int ns = 0;
      const int room = D_N - nk;
      // serial greedy resolve: register/SALU only, no LDS, no IoU
      while (todo) {
        if (ns == room) break;
        int j = __ffsll((unsigned long long)todo) - 1;
        surv |= 1ULL << j;
        ++ns;
        todo &= ~(1ULL << j);
        bool msup = (col >> j) & 1ULL;
        unsigned long long supj = __ballot(msup);
        todo &= ~supj;
      }
      if ((surv >> lane) & 1ULL) {
        int my = nk + __popcll(surv & ((1ULL << lane) - 1ULL));
        keptb[my] = cur;
        kepta[my] = area;
        keptr[my] = c0 + lane;
      }
      if (lane == 0) s_nk = nk + ns;
    }
    __syncthreads();
    if (s_nk >= D_N) break;
  }

  const int nkf = s_nk;
  for (int k = tid; k < nkf; k += 256) {
    int r = keptr[k];
    unsigned sb = (unsigned)(sorted[r] >> 32);
    kept_key[(size_t)task * D_N + k] =
        ((unsigned long long)sb << 32) |
        (unsigned)(0xFFFFFFFFu - (unsigned)(c * K_TOP + r));
  }
  if (tid == 0) kept_cnt[task] = nkf;
}

// ---------------------------------------------------------------------------
// K4: per-image top-200 of survivor keys via histogram rank-scatter.
//     Score bits live in u64 key bits [57:46] -> monotone 12-bit bin
//     (scores in (0.01,1]). 1024 threads/block. Histogram + wave-parallel
//     descending prefix + scatter + per-bin insertion sorts (4 bins/thread).
//     Legacy radix+bitonic fallback if a needed bin straddles slot 1024.
// ---------------------------------------------------------------------------
__global__ __launch_bounds__(K4_T) void k4_sel(
    const unsigned long long* __restrict__ kept_key,
    const int* __restrict__ kept_cnt, int* __restrict__ pick_flat)
{
  __shared__ __align__(16) int hist[4096];
  __shared__ unsigned long long sorted[1024];
  __shared__ int chunk[256];
  __shared__ int res[2];
  __shared__ int s_total;
  __shared__ int s_bad;
  __shared__ int s_lcnt;
  __shared__ int s_cnts[FG_N];
  const int b = blockIdx.x;
  const int tid = threadIdx.x;
  const unsigned long long* kb = kept_key + (size_t)b * FG_N * D_N;

  if (tid < FG_N) s_cnts[tid] = kept_cnt[b * FG_N + tid];
  for (int i = tid; i < 4096; i += K4_T) hist[i] = 0;
  if (tid == 0) s_bad = 0;
  __syncthreads();

  for (int idx = tid; idx < FG_N * D_N; idx += K4_T) {
    int c = idx / D_N, r = idx - c * D_N;
    if (r < s_cnts[c])
      atomicAdd(&hist[(int)((kb[idx] >> 46) & 0xFFFull)], 1);
  }
  __syncthreads();
  if (tid < 256) {
    int s = 0;
    for (int i = 0; i < 16; ++i) s += hist[tid * 16 + i];
    chunk[tid] = s;
  }
  __syncthreads();
  desc_scan256(chunk, &s_total, tid);
  __syncthreads();
  if (tid < 256) {
    int acc = chunk[tid];
    for (int i = 15; i >= 0; --i) {
      int bn = tid * 16 + i;
      int h = hist[bn];
      hist[bn] = acc;
      acc += h;
    }
  }
  __syncthreads();
  const int total = s_total;
  const int npick = total < D_N ? total : D_N;

  for (int idx = tid; idx < FG_N * D_N; idx += K4_T) {
    int c = idx / D_N, r = idx - c * D_N;
    if (r < s_cnts[c]) {
      unsigned long long k = kb[idx];
      int pos = atomicAdd(&hist[(int)((k >> 46) & 0xFFFull)], 1);
      if (pos < 1024) sorted[pos] = k;
    }
  }
  __syncthreads();
  for (int i = 0; i < 4; ++i) {
    int bn = tid * 4 + i;
    int end0 = hist[bn];
    int start = (bn < 4095) ? hist[bn + 1] : 0;
    int cb = end0 - start;
    if (cb > 1 && start < D_N) {
      if (end0 > 1024) { s_bad = 1; continue; }   // drop requires cb>824
      for (int q = start + 1; q < end0; ++q) {
        unsigned long long v = sorted[q];
        int j = q - 1;
        while (j >= start && sorted[j] < v) { sorted[j + 1] = sorted[j]; --j; }
        sorted[j + 1] = v;
      }
    }
  }
  __syncthreads();

  if (s_bad) {
    // ---------- exact legacy fallback: radix select + bitonic 1024 --------
    for (int i = tid; i < 4096; i += K4_T) hist[i] = 0;
    if (tid == 0) s_lcnt = 0;
    __syncthreads();
    for (int idx = tid; idx < FG_N * D_N; idx += K4_T) {
      int c = idx / D_N, r = idx - c * D_N;
      if (r < s_cnts[c]) {
        unsigned long long k = kb[idx];
        atomicAdd(&hist[(int)(k >> 52)], 1);
      }
    }
    __syncthreads();
    unsigned cutoff32 = 1u;
    if (total > D_N) {
      int need = D_N;
      scan_select(hist, 4096, need, tid, chunk, res);
      const unsigned b1 = (unsigned)res[0];
      const int above1 = res[1];
      const int in1 = hist[b1];
      __syncthreads();
      if (above1 + in1 <= 1024) {
        cutoff32 = b1 << 20;
      } else {
        need -= above1;
        for (int i = tid; i < 4096; i += K4_T) hist[i] = 0;
        __syncthreads();
        for (int idx = tid; idx < FG_N * D_N; idx += K4_T) {
          int c = idx / D_N, r = idx - c * D_N;
          if (r < s_cnts[c]) {
            unsigned long long k = kb[idx];
            if ((unsigned)(k >> 52) == b1)
              atomicAdd(&hist[(int)((k >> 40) & 0xFFFull)], 1);
          }
        }
        __syncthreads();
        scan_select(hist, 4096, need, tid, chunk, res);
        const unsigned b2 = (unsigned)res[0];
        need -= res[1];
        const unsigned pre12 = (b1 << 12) | b2;
        __syncthreads();
        if (tid < 256) hist[tid] = 0;
        __syncthreads();
        for (int idx = tid; idx < FG_N * D_N; idx += K4_T) {
          int c = idx / D_N, r = idx - c * D_N;
          if (r < s_cnts[c]) {
            unsigned long long k = kb[idx];
            if ((unsigned)(k >> 40) == pre12)
              atomicAdd(&hist[(int)((k >> 32) & 0xFFull)], 1);
          }
        }
        __syncthreads();
        scan_select(hist, 256, need, tid, chunk, res);
        cutoff32 = (pre12 << 8) | (unsigned)res[0];
        __syncthreads();
      }
    }
    const unsigned long long cutkey = (unsigned long long)cutoff32 << 32;
    for (int idx = tid; idx < FG_N * D_N; idx += K4_T) {
      int c = idx / D_N, r = idx - c * D_N;
      if (r < s_cnts[c]) {
        unsigned long long k = kb[idx];
        if (k >= cutkey) {
          int pos = atomicAdd(&s_lcnt, 1);
          if (pos < 1024) sorted[pos] = k;
        }
      }
    }
    __syncthreads();
    const int n = s_lcnt < 1024 ? s_lcnt : 1024;
    const int W = (n <= 256) ? 256 : (n <= 512) ? 512 : 1024;
    for (int i = tid; i < W; i += K4_T) if (i >= n) sorted[i] = 0ULL;
    __syncthreads();
    for (int kk = 2; kk <= W; kk <<= 1) {
      for (int jj = kk >> 1; jj > 0; jj >>= 1) {
        for (int i = tid; i < W; i += K4_T) {
          int ix = i ^ jj;
          if (ix > i) {
            unsigned long long va = sorted[i], vb = sorted[ix];
            bool desc = ((i & kk) == 0);
            if (desc ? (va < vb) : (va > vb)) { sorted[i] = vb; sorted[ix] = va; }
          }
        }
        __syncthreads();
      }
    }
  }

  for (int i = tid; i < D_N; i += K4_T) {
    int v = -1;
    if (i < npick)
      v = (int)(0xFFFFFFFFu - (unsigned)(sorted[i] & 0xFFFFFFFFull));
    pick_flat[b * D_N + i] = v;
  }
}

// ---------------------------------------------------------------------------
// K5: one wave per pick; packed u64 butterfly top-2 over 90 classes.
// ---------------------------------------------------------------------------
__global__ __launch_bounds__(256) void k5_out(
    const float* __restrict__ probs_t, const float* __restrict__ boxes,
    const int* __restrict__ topk_anchor, const int* __restrict__ pick_flat,
    float* __restrict__ out)
{
  const int wid  = threadIdx.x >> 6;
  const int lane = threadIdx.x & 63;
  const int pick = blockIdx.x * 4 + wid;
  const int b = pick / D_N;
  float* ob = out + (size_t)pick * 4;
  float* os = out + (size_t)B_N * D_N * 4 + (size_t)pick * 2;
  float* ol = out + (size_t)B_N * D_N * 6 + (size_t)pick * 2;
  const int flat = pick_flat[pick];
  if (flat < 0) {
    if (lane == 0) {
      ob[0] = 0.0f; ob[1] = 0.0f; ob[2] = 0.0f; ob[3] = 0.0f;
      os[0] = 0.0f; os[1] = 0.0f;
      ol[0] = 0.0f; ol[1] = 0.0f;
    }
    return;
  }
  const int c = flat / K_TOP;
  const int r = flat - c * K_TOP;
  const int anchor = topk_anchor[((size_t)b * FG_N + c) * K_TOP + r];
  const float* pp = probs_t + (size_t)b * FG_N * A_N + anchor;

  unsigned long long hi, lo = 0ULL;
  {
    float p = pp[(size_t)lane * A_N];
    hi = ((unsigned long long)__float_as_uint(p) << 32) | (0xFFFFFFFFu - (unsigned)lane);
  }
  if (lane + 64 < FG_N) {
    float p = pp[(size_t)(lane + 64) * A_N];
    unsigned long long k2 = ((unsigned long long)__float_as_uint(p) << 32) |
                            (0xFFFFFFFFu - (unsigned)(lane + 64));
    if (k2 > hi) { lo = hi; hi = k2; } else lo = k2;
  }
#pragma unroll
  for (int d = 1; d < 64; d <<= 1) {
    unsigned long long oh = __shfl_xor(hi, d, 64);
    unsigned long long ol2 = __shfl_xor(lo, d, 64);
    unsigned long long nh = hi > oh ? hi : oh;
    unsigned long long mn = hi > oh ? oh : hi;
    unsigned long long ml = lo > ol2 ? lo : ol2;
    hi = nh;
    lo = mn > ml ? mn : ml;
  }
  if (lane == 0) {
    float4 bp = *(const float4*)(boxes + ((size_t)b * A_N + anchor) * 4);
    *(float4*)ob = bp;
    unsigned cc1 = 0xFFFFFFFFu - (unsigned)(hi & 0xFFFFFFFFull);
    unsigned cc2 = 0xFFFFFFFFu - (unsigned)(lo & 0xFFFFFFFFull);
    os[0] = __uint_as_float((unsigned)(hi >> 32));
    os[1] = __uint_as_float((unsigned)(lo >> 32));
    ol[0] = (float)(cc1 + 1);
    ol[1] = (float)(cc2 + 1);
  }
}

// ---------------------------------------------------------------------------
extern "C" void kernel_launch(void* const* d_in, const int* in_sizes, int n_in,
                              void* d_out, int out_size, void* d_ws, size_t ws_size,
                              hipStream_t stream)
{
  (void)in_sizes; (void)n_in; (void)out_size; (void)ws_size;
  const float* cls = (const float*)d_in[0];
  const float* reg = (const float*)d_in[1];
  const float* anc = (const float*)d_in[2];

  char* w = (char*)d_ws;
  size_t off = 0;
  auto carve = [&](size_t bytes) -> char* {
    char* p = w + off;
    off += (bytes + 255) & ~(size_t)255;
    return p;
  };
  float* probs_t                = (float*)carve((size_t)B_N * FG_N * A_N * 4);
  float* boxes                  = (float*)carve((size_t)B_N * A_N * 4 * 4);
  int* topk_anchor              = (int*)carve((size_t)NTASK * K_TOP * 4);
  unsigned long long* kept_key  = (unsigned long long*)carve((size_t)NTASK * D_N * 8);
  int* kept_cnt                 = (int*)carve((size_t)NTASK * 4);
  int* pick_flat                = (int*)carve((size_t)B_N * D_N * 4);

  hipLaunchKernelGGL(k1_softmax_decode, dim3((B_N * A_N) / K1_ANB), dim3(K1B_T), 0, stream,
                     cls, reg, anc, probs_t, boxes);
  hipLaunchKernelGGL(k23_topk_nms, dim3(NTASK), dim3(256), 0, stream,
                     probs_t, boxes, topk_anchor, kept_key, kept_cnt);
  hipLaunchKernelGGL(k4_sel, dim3(B_N), dim3(K4_T), 0, stream,
                     kept_key, kept_cnt, pick_flat);
  hipLaunchKernelGGL(k5_out, dim3(B_N * D_N / 4), dim3(256), 0, stream,
                     probs_t, boxes, topk_anchor, pick_flat, (float*)d_out);
}